// Round 8
// baseline (191.235 us; speedup 1.0000x reference)
//
#include <hip/hip_runtime.h>

// Problem constants (fixed): B=2, S=2048, HIDDEN=1024, NHEADS=16, HEAD_DIM=64.
#define SEQ     2048
#define MROWS   4096
#define HID     1024
#define QKV3    3072
#define NH      16
#define HD      64
#define QSCALE  0.18033688f     // 0.125 * log2(e)  (folded into Q at gemm1)

typedef unsigned short u16;
typedef unsigned int   u32;
typedef __attribute__((ext_vector_type(8)))  short  bf16x8;   // 8 bf16 = 4 VGPRs
typedef __attribute__((ext_vector_type(4)))  float  floatx4;
typedef __attribute__((ext_vector_type(16))) float  floatx16;
typedef __attribute__((ext_vector_type(4)))  unsigned int u32x4;

__device__ __forceinline__ u16 f2bf(float f) {   // round-to-nearest-even
    u32 u = __builtin_bit_cast(u32, f);
    u += 0x7fffu + ((u >> 16) & 1u);
    return (u16)(u >> 16);
}

// raw v_exp_f32 (safe here: |s| < 9, no denormal/range issues)
#if __has_builtin(__builtin_amdgcn_exp2f)
__device__ __forceinline__ float fast_exp2(float x) { return __builtin_amdgcn_exp2f(x); }
#else
__device__ __forceinline__ float fast_exp2(float x) { return exp2f(x); }
#endif

// pack two fp32 -> two bf16 in one dword. low u16 = a, high = b.
#if __has_builtin(__builtin_amdgcn_cvt_pk_bf16_f32)
__device__ __forceinline__ u32 pack_bf(float a, float b) {
    auto r = __builtin_amdgcn_cvt_pk_bf16_f32(a, b);
    return __builtin_bit_cast(u32, r);
}
#else
__device__ __forceinline__ u32 pack_bf(float a, float b) {
    u32 ua = __builtin_bit_cast(u32, a) + 0x8000u;
    u32 ub = __builtin_bit_cast(u32, b) + 0x8000u;
    return __builtin_amdgcn_perm(ub, ua, 0x07060302u);
}
#endif

// v_permlane32_swap_b32: x.high <-> y.low  =>  x' = {x.low | y.low},
// y' = {x.high | y.high} (2x2 half-wave transpose; T12 recipe, m214v22).
__device__ __forceinline__ void plane_swap(u32 &x, u32 &y) {
#if __has_builtin(__builtin_amdgcn_permlane32_swap)
    typedef __attribute__((ext_vector_type(2))) unsigned int u32x2;
    u32x2 r = __builtin_amdgcn_permlane32_swap(x, y, false, false);
    x = r[0]; y = r[1];
#else
    asm volatile("v_permlane32_swap_b32 %0, %1" : "+v"(x), "+v"(y));
#endif
}

// async global->LDS, 16B/lane; LDS dest = wave-uniform base + lane*16
__device__ __forceinline__ void async_cp16(const void* g, void* l) {
    __builtin_amdgcn_global_load_lds(
        (const __attribute__((address_space(1))) unsigned int*)g,
        (__attribute__((address_space(3))) unsigned int*)l, 16, 0, 0);
}

// ---------------------------------------------------------------------------
// Single fused fp32->bf16 conversion over x | w_qkv | w_o (one launch).
// ---------------------------------------------------------------------------
#define N4_X   (MROWS * HID / 4)
#define N4_WQ  (QKV3 * HID / 4)
#define N4_WO  (HID * HID / 4)
__global__ void cvt_all(const float* __restrict__ x, const float* __restrict__ wq,
                        const float* __restrict__ wo, u16* __restrict__ xb,
                        u16* __restrict__ wqb, u16* __restrict__ wob) {
    int i = blockIdx.x * blockDim.x + threadIdx.x;
    const float* src; u16* dst; int k;
    if (i < N4_X)                { src = x;  dst = xb;  k = i; }
    else if (i < N4_X + N4_WQ)   { src = wq; dst = wqb; k = i - N4_X; }
    else                         { src = wo; dst = wob; k = i - N4_X - N4_WQ; }
    float4 v = ((const float4*)src)[k];
    uint2 o = {pack_bf(v.x, v.y), pack_bf(v.z, v.w)};
    ((uint2*)dst)[k] = o;
}

// ---------------------------------------------------------------------------
// C = A @ B^T + bias.  A:[M,K] bf16, B:[N,K] bf16, row-major.
// Tile 128 x NT (NT=128 or 64), BK=32, 4 waves, 16x16x32 bf16 MFMA.
// (byte-identical to round-7 verified source; V-epilogue-via-LDS was
// neutral but passed — kept to avoid churn)
// ---------------------------------------------------------------------------
template <int MODE, int NT>
__global__ __launch_bounds__(256)
void gemm_bf16_nt(const u16* __restrict__ A, const u16* __restrict__ B,
                  const float* __restrict__ bias, float* __restrict__ Cout,
                  int M, int N, int K,
                  u16* __restrict__ q_ws, u16* __restrict__ k_ws,
                  u16* __restrict__ vt_ws) {
    constexpr int WN = NT / 2;     // per-wave n extent
    constexpr int NJ = WN / 16;    // n-frags per wave
    // one blob: As[2][128*32] | Bs[2][NT*32]; V-epilogue aliases all of it
    __shared__ __align__(16) u16 smemS[2 * 128 * 32 + 2 * NT * 32];
    auto As_ = [&](int bb) -> u16* { return smemS + bb * 4096; };
    auto Bs_ = [&](int bb) -> u16* { return smemS + 8192 + bb * (NT * 32); };
    const int t  = (int)threadIdx.x;
    const int w  = t >> 6, l = t & 63;
    const int wr = w >> 1, wc = w & 1;
    const int m0 = (int)blockIdx.y * 128, n0 = (int)blockIdx.x * NT;
    const int lrow = l >> 2;
    const int lseg = ((l & 3) ^ ((l >> 3) & 3)) * 8;    // swizzled global seg
    const int fm = l & 15, fq = l >> 4;
    const int fseg = (fq ^ ((fm >> 1) & 3)) * 8;        // swizzled frag seg

    auto stage = [&](int k0, int bb) {
#pragma unroll
        for (int rep = 0; rep < 2; ++rep) {
            const int chunk = w + rep * 4;
            const int row   = chunk * 16 + lrow;
            async_cp16(A + (size_t)(m0 + row) * K + k0 + lseg, As_(bb) + chunk * 512);
            if (NT == 128 || rep == 0)
                async_cp16(B + (size_t)(n0 + row) * K + k0 + lseg, Bs_(bb) + chunk * 512);
        }
    };

    floatx4 acc[4][NJ];
#pragma unroll
    for (int i = 0; i < 4; ++i)
#pragma unroll
        for (int j = 0; j < NJ; ++j) acc[i][j] = (floatx4)(0.f);

    const int T = K >> 5;
    stage(0, 0);
    for (int tt = 0; tt < T; ++tt) {
        const int cur = tt & 1;
        __syncthreads();                    // drains stage(tt) (overlapped)
        if (tt + 1 < T) stage((tt + 1) << 5, cur ^ 1);
        bf16x8 af[4], bfr[NJ];
#pragma unroll
        for (int i = 0; i < 4; ++i)
            af[i] = *(const bf16x8*)(As_(cur) + (wr * 64 + i * 16 + fm) * 32 + fseg);
#pragma unroll
        for (int j = 0; j < NJ; ++j)
            bfr[j] = *(const bf16x8*)(Bs_(cur) + (wc * WN + j * 16 + fm) * 32 + fseg);
#pragma unroll
        for (int i = 0; i < 4; ++i)
#pragma unroll
            for (int j = 0; j < NJ; ++j)
                acc[i][j] = __builtin_amdgcn_mfma_f32_16x16x32_bf16(
                    af[i], bfr[j], acc[i][j], 0, 0, 0);
    }

    // ---- V-region epilogue via LDS (MODE 1, cols 2048..3071) ----
    if (MODE == 1 && (n0 >> 10) == 2) {
        __syncthreads();                      // last tile's ds_reads complete
        u32* VT = (u32*)smemS;                // [128 d][64 s-pair] u32 = 32 KB
#pragma unroll
        for (int j = 0; j < NJ; ++j) {
            const int lc = wc * WN + j * 16 + fm;       // block-local col 0..127
            const float bv = bias[n0 + lc];
#pragma unroll
            for (int i = 0; i < 4; ++i) {
                const int rl = wr * 64 + i * 16 + fq * 4;   // block-local row
                const int wp = rl >> 1;                     // even
                uint2 pr = {pack_bf(acc[i][j][0] + bv, acc[i][j][1] + bv),
                            pack_bf(acc[i][j][2] + bv, acc[i][j][3] + bv)};
                *(uint2*)&VT[lc * 64 + (wp ^ ((lc & 7) << 3))] = pr;
            }
        }
        __syncthreads();
        const int lc = t >> 1, h2 = t & 1;
        const int gcol = n0 + lc;
        const int hh = (gcol >> 6) & 15, d = gcol & 63;
        const int b = m0 >> 11;
        u16* __restrict__ dstp = vt_ws
            + ((size_t)(b * NH + hh) * HD + d) * SEQ + (m0 & 2047) + h2 * 64;
        const int X = (lc & 7) << 3;
#pragma unroll
        for (int c = 0; c < 8; ++c) {
            u32x4 v = *(const u32x4*)&VT[lc * 64 + ((h2 * 32 + c * 4) ^ X)];
            *(u32x4*)&dstp[c * 8] = v;
        }
        return;
    }

    // epilogue: C/D layout col=lane&15, row=quad*4+reg (Q/K + MODE 0 paths)
#pragma unroll
    for (int j = 0; j < NJ; ++j) {
        const int col = n0 + wc * WN + j * 16 + fm;
        const float bv = bias[col];
        const int region = col >> 10;                  // block-uniform in MODE 1
        const int hh = (col >> 6) & 15, d = col & 63;
#pragma unroll
        for (int i = 0; i < 4; ++i) {
            const int row0 = m0 + wr * 64 + i * 16 + fq * 4;
            if (MODE == 0) {
#pragma unroll
                for (int r = 0; r < 4; ++r)
                    Cout[(size_t)(row0 + r) * N + col] = acc[i][j][r] + bv;
            } else {
                u16* __restrict__ dst = (region == 0) ? q_ws : k_ws;
                const float sc = (region == 0) ? QSCALE : 1.0f;
#pragma unroll
                for (int r = 0; r < 4; ++r) {
                    const int row = row0 + r;
                    const int b = row >> 11, s = row & 2047;
                    dst[((size_t)(b * NH + hh) * SEQ + s) * HD + d] =
                        f2bf((acc[i][j][r] + bv) * sc);
                }
            }
        }
    }
}

// ---------------------------------------------------------------------------
// Flash attention, 32x32x16 MFMA, operand-swapped (S^T = K Q^T, O^T = V^T P^T),
// shift-free softmax p = exp2(s_scaled). 4 waves x 32 q (qblk 128), BK=128.
// ROUND-17 (ILP package on the r4-verified 48.2us structure): cycle audit
// shows the kernel is dependency-latency-bound at a structurally-capped
// 2 waves/SIMD (65536 q-rows / 32 per wave = 2048 waves exactly). Pipes sum
// to ~1-1.5K cyc/iter but iters take ~3.6K CU-cyc -> serial chains dominate.
// Deltas vs r4 (attn only; gemms byte-identical):
//  1. PV accumulator split by ks2 parity: po[dt][par] -> 4 chains of depth 4
//     (was oacc[2]: 2 chains of depth 8 @ ~24cyc dependent-MFMA latency).
//     Merged once after the loop (32 f32 adds).
//  2. psum chain split into two alternating float2 accumulators (32 -> 16
//     sequential adds per iter).
//  3. s_setprio(1) re-added around QK and PV MFMA clusters (m191: +4-7% attn;
//     the 2 co-resident blocks are barrier-desynced -> arbitration pays).
// VGPR 124 -> ~158 (cap 3 waves/SIMD >= 2 resident; no occupancy change).
// ---------------------------------------------------------------------------
__global__ __launch_bounds__(256, 2)
void attn_mfma(const u16* __restrict__ qw, const u16* __restrict__ kw,
               const u16* __restrict__ vtw, u16* __restrict__ attn) {
    __shared__ u16 Ks [2][2][64 * 64];   // [buf][subtile][key][d], swizzled
    __shared__ u16 Vts[2][2][64 * 64];   // [buf][subtile][d][key], swizzled

    const int bh   = (int)blockIdx.x;
    const int qblk = (int)blockIdx.y * 128;
    const int t = (int)threadIdx.x;
    const int w = t >> 6, l = t & 63;          // 4 waves, 32 q each
    const int ql = l & 31, h = l >> 5;         // 32x32 frag: col lane, half
    const int srow = l >> 3, sseg = l & 7;     // staging row/seg in chunk
    const size_t headSD = (size_t)bh * SEQ * HD;
    const size_t headDS = (size_t)bh * HD * SEQ;

    // wave w stages chunks 2w, 2w+1 (8 rows each) of K and V^T, both subtiles
    auto stage = [&](int it, int bb) {
#pragma unroll
        for (int half = 0; half < 2; ++half) {
            const int kt = it * 2 + half;
#pragma unroll
            for (int rep = 0; rep < 2; ++rep) {
                const int chunk = w * 2 + rep;     // 0..7
                async_cp16(kw + headSD + (size_t)(kt * 64 + chunk * 8 + srow) * HD
                               + ((sseg ^ srow) * 8), &Ks[bb][half][chunk * 512]);
                async_cp16(vtw + headDS + (size_t)(chunk * 8 + srow) * SEQ + kt * 64
                               + ((sseg ^ srow) * 8), &Vts[bb][half][chunk * 512]);
            }
        }
    };

    // Q as B-operand frags: B[k = ks*16 + h*8 + e][n = q = ql], from global
    bf16x8 qa[4];
#pragma unroll
    for (int ks = 0; ks < 4; ++ks)
        qa[ks] = *(const bf16x8*)(qw + headSD
            + (size_t)(qblk + w * 32 + ql) * HD + ks * 16 + h * 8);

    const floatx16 z16 = (floatx16)(0.f);      // persistent zero C-operand
    floatx16 po[2][2];                         // [dt][ks2-parity] PV partials
    po[0][0] = z16; po[0][1] = z16; po[1][0] = z16; po[1][1] = z16;
    float2 psA = {0.f, 0.f}, psB = {0.f, 0.f};

    stage(0, 0);
    for (int it = 0; it < SEQ / 128; ++it) {
        const int cur = it & 1;
        __syncthreads();                    // drains stage(it) (overlapped)
        if (it + 1 < SEQ / 128) stage(it + 1, cur ^ 1);

        // S^T = K Q^T for BOTH subtiles (4 independent chains of depth 4)
        floatx16 sacc[2][2];
        __builtin_amdgcn_s_setprio(1);
#pragma unroll
        for (int half = 0; half < 2; ++half) {
#pragma unroll
            for (int ks = 0; ks < 4; ++ks) {
                const int seg = ((ks * 2 + h) ^ (ql & 7)) * 8;
#pragma unroll
                for (int t2 = 0; t2 < 2; ++t2) {
                    bf16x8 ka = *(const bf16x8*)&Ks[cur][half][(t2 * 32 + ql) * 64 + seg];
                    sacc[half][t2] = __builtin_amdgcn_mfma_f32_32x32x16_bf16(
                        ka, qa[ks], (ks == 0) ? z16 : sacc[half][t2], 0, 0, 0);
                }
            }
        }
        __builtin_amdgcn_s_setprio(0);

        // softmax + in-register P redistribution (T12) + PV, per subtile.
        // lane holds P(key = t2*32 + (r&3)+8*(r>>2)+4h, q=ql);
        // cvt_pk pairs + permlane32_swap -> PV B-frags, zero LDS.
#pragma unroll
        for (int half = 0; half < 2; ++half) {
#pragma unroll
            for (int t2 = 0; t2 < 2; ++t2) {
                u32 aw[8];
#pragma unroll
                for (int i = 0; i < 8; ++i) {
                    const float p0 = fast_exp2(sacc[half][t2][2 * i]);
                    const float p1 = fast_exp2(sacc[half][t2][2 * i + 1]);
                    if (t2 == 0) psA += float2{p0, p1};
                    else         psB += float2{p0, p1};
                    aw[i] = pack_bf(p0, p1);
                }
                plane_swap(aw[0], aw[2]); plane_swap(aw[1], aw[3]);
                plane_swap(aw[4], aw[6]); plane_swap(aw[5], aw[7]);

                __builtin_amdgcn_s_setprio(1);
#pragma unroll
                for (int ks2 = 0; ks2 < 2; ++ks2) {
                    u32x4 pw = {aw[4 * ks2 + 0], aw[4 * ks2 + 1],
                                aw[4 * ks2 + 2], aw[4 * ks2 + 3]};
                    bf16x8 pb = __builtin_bit_cast(bf16x8, pw);
                    const int seg = ((t2 * 4 + ks2 * 2 + h) ^ (ql & 7)) * 8;
#pragma unroll
                    for (int dt = 0; dt < 2; ++dt) {
                        bf16x8 va = *(const bf16x8*)&Vts[cur][half][(dt * 32 + ql) * 64 + seg];
                        po[dt][ks2] = __builtin_amdgcn_mfma_f32_32x32x16_bf16(
                            va, pb, po[dt][ks2], 0, 0, 0);
                    }
                }
                __builtin_amdgcn_s_setprio(0);
            }
        }
    }

    // merge PV partials; psum(q): halves hold complementary key sets
    floatx16 oacc[2];
    oacc[0] = po[0][0] + po[0][1];
    oacc[1] = po[1][0] + po[1][1];
    float psum = (psA.x + psA.y) + (psB.x + psB.y);
    psum += __shfl_xor(psum, 32);
    const float inv = 1.0f / psum;

    // epilogue: O^T rows = d = (r&3) + 8*(r>>2) + 4h + 32*dt; col q = ql
    const int b = bh >> 4, head = bh & 15;
    u16* __restrict__ orow =
        attn + (size_t)(b * SEQ + qblk + w * 32 + ql) * HID + head * HD;
#pragma unroll
    for (int dt = 0; dt < 2; ++dt) {
#pragma unroll
        for (int g = 0; g < 4; ++g) {
            uint2 o = {pack_bf(oacc[dt][g * 4 + 0] * inv, oacc[dt][g * 4 + 1] * inv),
                       pack_bf(oacc[dt][g * 4 + 2] * inv, oacc[dt][g * 4 + 3] * inv)};
            *(uint2*)&orow[dt * 32 + g * 8 + h * 4] = o;
        }
    }
}

// ---------------------------------------------------------------------------
extern "C" void kernel_launch(void* const* d_in, const int* in_sizes, int n_in,
                              void* d_out, int out_size, void* d_ws, size_t ws_size,
                              hipStream_t stream) {
    const float* x     = (const float*)d_in[0];
    const float* w_qkv = (const float*)d_in[1];
    const float* b_qkv = (const float*)d_in[2];
    const float* w_o   = (const float*)d_in[3];
    const float* b_o   = (const float*)d_in[4];
    float* outp = (float*)d_out;

    u16* xb    = (u16*)d_ws;
    u16* wqkvb = xb    + (size_t)MROWS * HID;
    u16* wob   = wqkvb + (size_t)QKV3 * HID;
    u16* q_ws  = wob   + (size_t)HID * HID;
    u16* k_ws  = q_ws  + (size_t)MROWS * HID;
    u16* vt_ws = k_ws  + (size_t)MROWS * HID;
    u16* attnb = vt_ws + (size_t)MROWS * HID;

    const int blk = 256;
    cvt_all<<<(N4_X + N4_WQ + N4_WO) / blk, blk, 0, stream>>>(
        x, w_qkv, w_o, xb, wqkvb, wob);

    gemm_bf16_nt<1, 128><<<dim3(QKV3 / 128, MROWS / 128), blk, 0, stream>>>(
        xb, wqkvb, b_qkv, nullptr, MROWS, QKV3, HID, q_ws, k_ws, vt_ws);

    attn_mfma<<<dim3(NH * 2, SEQ / 128), 256, 0, stream>>>(q_ws, k_ws, vt_ws, attnb);

    gemm_bf16_nt<0, 64><<<dim3(HID / 64, MROWS / 128), blk, 0, stream>>>(
        attnb, wob, b_o, outp, MROWS, HID, HID, nullptr, nullptr, nullptr);
}

// Round 9
// 184.239 us; speedup vs baseline: 1.0380x; 1.0380x over previous
//
#include <hip/hip_runtime.h>

// Problem constants (fixed): B=2, S=2048, HIDDEN=1024, NHEADS=16, HEAD_DIM=64.
#define SEQ     2048
#define MROWS   4096
#define HID     1024
#define QKV3    3072
#define NH      16
#define HD      64
#define QSCALE  0.18033688f     // 0.125 * log2(e)  (folded into Q at gemm1)

typedef unsigned short u16;
typedef unsigned int   u32;
typedef __attribute__((ext_vector_type(8)))  short  bf16x8;   // 8 bf16 = 4 VGPRs
typedef __attribute__((ext_vector_type(4)))  float  floatx4;
typedef __attribute__((ext_vector_type(16))) float  floatx16;
typedef __attribute__((ext_vector_type(4)))  unsigned int u32x4;

__device__ __forceinline__ u16 f2bf(float f) {   // round-to-nearest-even
    u32 u = __builtin_bit_cast(u32, f);
    u += 0x7fffu + ((u >> 16) & 1u);
    return (u16)(u >> 16);
}

// raw v_exp_f32 (safe here: |s| < 9, no denormal/range issues)
#if __has_builtin(__builtin_amdgcn_exp2f)
__device__ __forceinline__ float fast_exp2(float x) { return __builtin_amdgcn_exp2f(x); }
#else
__device__ __forceinline__ float fast_exp2(float x) { return exp2f(x); }
#endif

// pack two fp32 -> two bf16 in one dword. low u16 = a, high = b.
#if __has_builtin(__builtin_amdgcn_cvt_pk_bf16_f32)
__device__ __forceinline__ u32 pack_bf(float a, float b) {
    auto r = __builtin_amdgcn_cvt_pk_bf16_f32(a, b);
    return __builtin_bit_cast(u32, r);
}
#else
__device__ __forceinline__ u32 pack_bf(float a, float b) {
    u32 ua = __builtin_bit_cast(u32, a) + 0x8000u;
    u32 ub = __builtin_bit_cast(u32, b) + 0x8000u;
    return __builtin_amdgcn_perm(ub, ua, 0x07060302u);
}
#endif

// v_permlane32_swap_b32: x.high <-> y.low  =>  x' = {x.low | y.low},
// y' = {x.high | y.high} (2x2 half-wave transpose; T12 recipe, m214v22).
__device__ __forceinline__ void plane_swap(u32 &x, u32 &y) {
#if __has_builtin(__builtin_amdgcn_permlane32_swap)
    typedef __attribute__((ext_vector_type(2))) unsigned int u32x2;
    u32x2 r = __builtin_amdgcn_permlane32_swap(x, y, false, false);
    x = r[0]; y = r[1];
#else
    asm volatile("v_permlane32_swap_b32 %0, %1" : "+v"(x), "+v"(y));
#endif
}

// async global->LDS, 16B/lane; LDS dest = wave-uniform base + lane*16
__device__ __forceinline__ void async_cp16(const void* g, void* l) {
    __builtin_amdgcn_global_load_lds(
        (const __attribute__((address_space(1))) unsigned int*)g,
        (__attribute__((address_space(3))) unsigned int*)l, 16, 0, 0);
}

// ---------------------------------------------------------------------------
// Single fused fp32->bf16 conversion over x | w_qkv | w_o (one launch).
// ---------------------------------------------------------------------------
#define N4_X   (MROWS * HID / 4)
#define N4_WQ  (QKV3 * HID / 4)
#define N4_WO  (HID * HID / 4)
__global__ void cvt_all(const float* __restrict__ x, const float* __restrict__ wq,
                        const float* __restrict__ wo, u16* __restrict__ xb,
                        u16* __restrict__ wqb, u16* __restrict__ wob) {
    int i = blockIdx.x * blockDim.x + threadIdx.x;
    const float* src; u16* dst; int k;
    if (i < N4_X)                { src = x;  dst = xb;  k = i; }
    else if (i < N4_X + N4_WQ)   { src = wq; dst = wqb; k = i - N4_X; }
    else                         { src = wo; dst = wob; k = i - N4_X - N4_WQ; }
    float4 v = ((const float4*)src)[k];
    uint2 o = {pack_bf(v.x, v.y), pack_bf(v.z, v.w)};
    ((uint2*)dst)[k] = o;
}

// ---------------------------------------------------------------------------
// C = A @ B^T + bias.  A:[M,K] bf16, B:[N,K] bf16, row-major.
// Tile 128 x NT (NT=128 or 64), BK=32, 4 waves.
// ROUND-18: MFMA unit switched 16x16x32 -> 32x32x16 (m119: 3966 vs 3378
// FLOP/cyc; half the issue slots, same 8 ds_read_b128/iter, same AGPR).
// Operand/CD mappings reused from the session-verified attn kernel:
// op[row=ql][k=h*8+e]; D: col=ql, row=(r&3)+8*(r>>2)+4h. LDS read seg =
// (ks*2+h) ^ ((ql>>1)&3) — matches stage-side XOR (row bits 1-2 = ql bits
// 1-2). Staging loop, dbuf, V-epilogue-via-LDS layout all unchanged.
// ---------------------------------------------------------------------------
template <int MODE, int NT>
__global__ __launch_bounds__(256)
void gemm_bf16_nt(const u16* __restrict__ A, const u16* __restrict__ B,
                  const float* __restrict__ bias, float* __restrict__ Cout,
                  int M, int N, int K,
                  u16* __restrict__ q_ws, u16* __restrict__ k_ws,
                  u16* __restrict__ vt_ws) {
    constexpr int WN = NT / 2;     // per-wave n extent (64 or 32)
    constexpr int NJ = WN / 32;    // 32-wide n-frags per wave (2 or 1)
    // one blob: As[2][128*32] | Bs[2][NT*32]; V-epilogue aliases all of it
    __shared__ __align__(16) u16 smemS[2 * 128 * 32 + 2 * NT * 32];
    auto As_ = [&](int bb) -> u16* { return smemS + bb * 4096; };
    auto Bs_ = [&](int bb) -> u16* { return smemS + 8192 + bb * (NT * 32); };
    const int t  = (int)threadIdx.x;
    const int w  = t >> 6, l = t & 63;
    const int wr = w >> 1, wc = w & 1;
    const int m0 = (int)blockIdx.y * 128, n0 = (int)blockIdx.x * NT;
    const int lrow = l >> 2;
    const int lseg = ((l & 3) ^ ((l >> 3) & 3)) * 8;    // swizzled global seg
    const int ql = l & 31, h = l >> 5;                  // 32x32 frag coords

    auto stage = [&](int k0, int bb) {
#pragma unroll
        for (int rep = 0; rep < 2; ++rep) {
            const int chunk = w + rep * 4;
            const int row   = chunk * 16 + lrow;
            async_cp16(A + (size_t)(m0 + row) * K + k0 + lseg, As_(bb) + chunk * 512);
            if (NT == 128 || rep == 0)
                async_cp16(B + (size_t)(n0 + row) * K + k0 + lseg, Bs_(bb) + chunk * 512);
        }
    };

    const floatx16 z16 = (floatx16)(0.f);
    floatx16 acc[2][NJ];
#pragma unroll
    for (int i = 0; i < 2; ++i)
#pragma unroll
        for (int j = 0; j < NJ; ++j) acc[i][j] = z16;

    const int T = K >> 5;
    stage(0, 0);
    for (int tt = 0; tt < T; ++tt) {
        const int cur = tt & 1;
        __syncthreads();                    // drains stage(tt) (overlapped)
        if (tt + 1 < T) stage((tt + 1) << 5, cur ^ 1);
        bf16x8 af[2][2], bfr[NJ][2];
#pragma unroll
        for (int i = 0; i < 2; ++i)
#pragma unroll
            for (int ks = 0; ks < 2; ++ks) {
                const int row = wr * 64 + i * 32 + ql;
                const int seg = ((ks * 2 + h) ^ ((ql >> 1) & 3)) * 8;
                af[i][ks] = *(const bf16x8*)(As_(cur) + row * 32 + seg);
            }
#pragma unroll
        for (int j = 0; j < NJ; ++j)
#pragma unroll
            for (int ks = 0; ks < 2; ++ks) {
                const int row = wc * WN + j * 32 + ql;
                const int seg = ((ks * 2 + h) ^ ((ql >> 1) & 3)) * 8;
                bfr[j][ks] = *(const bf16x8*)(Bs_(cur) + row * 32 + seg);
            }
#pragma unroll
        for (int i = 0; i < 2; ++i)
#pragma unroll
            for (int j = 0; j < NJ; ++j)
#pragma unroll
                for (int ks = 0; ks < 2; ++ks)
                    acc[i][j] = __builtin_amdgcn_mfma_f32_32x32x16_bf16(
                        af[i][ks], bfr[j][ks], acc[i][j], 0, 0, 0);
    }

    // ---- V-region epilogue via LDS (MODE 1, cols 2048..3071) ----
    if (MODE == 1 && (n0 >> 10) == 2) {
        __syncthreads();                      // last tile's ds_reads complete
        u32* VT = (u32*)smemS;                // [128 d][64 s-pair] u32 = 32 KB
#pragma unroll
        for (int j = 0; j < NJ; ++j) {
            const int lc = wc * WN + j * 32 + ql;       // block-local col 0..127
            const float bv = bias[n0 + lc];
#pragma unroll
            for (int i = 0; i < 2; ++i) {
#pragma unroll
                for (int g = 0; g < 4; ++g) {
                    // quad g = 4 consecutive rows rl0 .. rl0+3
                    const int rl0 = wr * 64 + i * 32 + g * 8 + h * 4;
                    const int wp = rl0 >> 1;            // even
                    uint2 pr = {pack_bf(acc[i][j][4*g+0] + bv, acc[i][j][4*g+1] + bv),
                                pack_bf(acc[i][j][4*g+2] + bv, acc[i][j][4*g+3] + bv)};
                    *(uint2*)&VT[lc * 64 + (wp ^ ((lc & 7) << 3))] = pr;
                }
            }
        }
        __syncthreads();
        const int lc = t >> 1, h2 = t & 1;
        const int gcol = n0 + lc;
        const int hh = (gcol >> 6) & 15, d = gcol & 63;
        const int b = m0 >> 11;
        u16* __restrict__ dstp = vt_ws
            + ((size_t)(b * NH + hh) * HD + d) * SEQ + (m0 & 2047) + h2 * 64;
        const int X = (lc & 7) << 3;
#pragma unroll
        for (int c = 0; c < 8; ++c) {
            u32x4 v = *(const u32x4*)&VT[lc * 64 + ((h2 * 32 + c * 4) ^ X)];
            *(u32x4*)&dstp[c * 8] = v;
        }
        return;
    }

    // epilogue: 32x32 C/D layout col = ql, row = (r&3) + 8*(r>>2) + 4h
#pragma unroll
    for (int j = 0; j < NJ; ++j) {
        const int col = n0 + wc * WN + j * 32 + ql;
        const float bv = bias[col];
        const int region = col >> 10;                  // block-uniform in MODE 1
        const int hh = (col >> 6) & 15, d = col & 63;
#pragma unroll
        for (int i = 0; i < 2; ++i) {
#pragma unroll
            for (int g = 0; g < 4; ++g) {
                const int row0 = m0 + wr * 64 + i * 32 + g * 8 + h * 4;
                if (MODE == 0) {
#pragma unroll
                    for (int r = 0; r < 4; ++r)
                        Cout[(size_t)(row0 + r) * N + col] = acc[i][j][4*g+r] + bv;
                } else {
                    u16* __restrict__ dst = (region == 0) ? q_ws : k_ws;
                    const float sc = (region == 0) ? QSCALE : 1.0f;
#pragma unroll
                    for (int r = 0; r < 4; ++r) {
                        const int row = row0 + r;
                        const int b = row >> 11, s = row & 2047;
                        dst[((size_t)(b * NH + hh) * SEQ + s) * HD + d] =
                            f2bf((acc[i][j][4*g+r] + bv) * sc);
                    }
                }
            }
        }
    }
}

// ---------------------------------------------------------------------------
// Flash attention — EXACT round-4/round-7 kernel (verified 48.2 us, twice).
// 32x32x16 MFMA, operand-swapped (S^T = K Q^T, O^T = V^T P^T), shift-free
// softmax p = exp2(s_scaled). 4 waves x 32 q (qblk 128), BK=128, T12
// in-register P redistribution. r6 key-split (68us) and r8 ILP/setprio
// package (56.5us) both regressed — this structure is the measured optimum;
// leaving it alone.
// ---------------------------------------------------------------------------
__global__ __launch_bounds__(256, 2)
void attn_mfma(const u16* __restrict__ qw, const u16* __restrict__ kw,
               const u16* __restrict__ vtw, u16* __restrict__ attn) {
    __shared__ u16 Ks [2][2][64 * 64];   // [buf][subtile][key][d], swizzled
    __shared__ u16 Vts[2][2][64 * 64];   // [buf][subtile][d][key], swizzled

    const int bh   = (int)blockIdx.x;
    const int qblk = (int)blockIdx.y * 128;
    const int t = (int)threadIdx.x;
    const int w = t >> 6, l = t & 63;          // 4 waves, 32 q each
    const int ql = l & 31, h = l >> 5;         // 32x32 frag: col lane, half
    const int srow = l >> 3, sseg = l & 7;     // staging row/seg in chunk
    const size_t headSD = (size_t)bh * SEQ * HD;
    const size_t headDS = (size_t)bh * HD * SEQ;

    // wave w stages chunks 2w, 2w+1 (8 rows each) of K and V^T, both subtiles
    auto stage = [&](int it, int bb) {
#pragma unroll
        for (int half = 0; half < 2; ++half) {
            const int kt = it * 2 + half;
#pragma unroll
            for (int rep = 0; rep < 2; ++rep) {
                const int chunk = w * 2 + rep;     // 0..7
                async_cp16(kw + headSD + (size_t)(kt * 64 + chunk * 8 + srow) * HD
                               + ((sseg ^ srow) * 8), &Ks[bb][half][chunk * 512]);
                async_cp16(vtw + headDS + (size_t)(chunk * 8 + srow) * SEQ + kt * 64
                               + ((sseg ^ srow) * 8), &Vts[bb][half][chunk * 512]);
            }
        }
    };

    // Q as B-operand frags: B[k = ks*16 + h*8 + e][n = q = ql], from global
    bf16x8 qa[4];
#pragma unroll
    for (int ks = 0; ks < 4; ++ks)
        qa[ks] = *(const bf16x8*)(qw + headSD
            + (size_t)(qblk + w * 32 + ql) * HD + ks * 16 + h * 8);

    const floatx16 z16 = (floatx16)(0.f);      // persistent zero C-operand
    floatx16 oacc[2];
    oacc[0] = z16; oacc[1] = z16;
    float2 psum2 = {0.f, 0.f};

    stage(0, 0);
    for (int it = 0; it < SEQ / 128; ++it) {
        const int cur = it & 1;
        __syncthreads();                    // drains stage(it) (overlapped)
        if (it + 1 < SEQ / 128) stage(it + 1, cur ^ 1);

        // S^T = K Q^T for BOTH subtiles first: sm_A VALU can then overlap
        // QK_B / PV_A MFMAs in the scheduler's single region.
        floatx16 sacc[2][2];
#pragma unroll
        for (int half = 0; half < 2; ++half) {
#pragma unroll
            for (int ks = 0; ks < 4; ++ks) {
                const int seg = ((ks * 2 + h) ^ (ql & 7)) * 8;
#pragma unroll
                for (int t2 = 0; t2 < 2; ++t2) {
                    bf16x8 ka = *(const bf16x8*)&Ks[cur][half][(t2 * 32 + ql) * 64 + seg];
                    sacc[half][t2] = __builtin_amdgcn_mfma_f32_32x32x16_bf16(
                        ka, qa[ks], (ks == 0) ? z16 : sacc[half][t2], 0, 0, 0);
                }
            }
        }

        // softmax + in-register P redistribution (T12) + PV, per subtile.
        // lane holds P(key = t2*32 + (r&3)+8*(r>>2)+4h, q=ql);
        // cvt_pk pairs + permlane32_swap -> PV B-frags, zero LDS.
#pragma unroll
        for (int half = 0; half < 2; ++half) {
#pragma unroll
            for (int t2 = 0; t2 < 2; ++t2) {
                u32 aw[8];
#pragma unroll
                for (int i = 0; i < 8; ++i) {
                    const float p0 = fast_exp2(sacc[half][t2][2 * i]);
                    const float p1 = fast_exp2(sacc[half][t2][2 * i + 1]);
                    psum2 += float2{p0, p1};
                    aw[i] = pack_bf(p0, p1);
                }
                plane_swap(aw[0], aw[2]); plane_swap(aw[1], aw[3]);
                plane_swap(aw[4], aw[6]); plane_swap(aw[5], aw[7]);

#pragma unroll
                for (int ks2 = 0; ks2 < 2; ++ks2) {
                    u32x4 pw = {aw[4 * ks2 + 0], aw[4 * ks2 + 1],
                                aw[4 * ks2 + 2], aw[4 * ks2 + 3]};
                    bf16x8 pb = __builtin_bit_cast(bf16x8, pw);
                    const int seg = ((t2 * 4 + ks2 * 2 + h) ^ (ql & 7)) * 8;
#pragma unroll
                    for (int dt = 0; dt < 2; ++dt) {
                        bf16x8 va = *(const bf16x8*)&Vts[cur][half][(dt * 32 + ql) * 64 + seg];
                        oacc[dt] = __builtin_amdgcn_mfma_f32_32x32x16_bf16(
                            va, pb, oacc[dt], 0, 0, 0);
                    }
                }
            }
        }
    }

    // psum(q): halves hold complementary key sets -> one xor-32 combine
    float psum = psum2.x + psum2.y;
    psum += __shfl_xor(psum, 32);
    const float inv = 1.0f / psum;

    // epilogue: O^T rows = d = (r&3) + 8*(r>>2) + 4h + 32*dt; col q = ql
    const int b = bh >> 4, head = bh & 15;
    u16* __restrict__ orow =
        attn + (size_t)(b * SEQ + qblk + w * 32 + ql) * HID + head * HD;
#pragma unroll
    for (int dt = 0; dt < 2; ++dt) {
#pragma unroll
        for (int g = 0; g < 4; ++g) {
            uint2 o = {pack_bf(oacc[dt][g * 4 + 0] * inv, oacc[dt][g * 4 + 1] * inv),
                       pack_bf(oacc[dt][g * 4 + 2] * inv, oacc[dt][g * 4 + 3] * inv)};
            *(uint2*)&orow[dt * 32 + g * 8 + h * 4] = o;
        }
    }
}

// ---------------------------------------------------------------------------
extern "C" void kernel_launch(void* const* d_in, const int* in_sizes, int n_in,
                              void* d_out, int out_size, void* d_ws, size_t ws_size,
                              hipStream_t stream) {
    const float* x     = (const float*)d_in[0];
    const float* w_qkv = (const float*)d_in[1];
    const float* b_qkv = (const float*)d_in[2];
    const float* w_o   = (const float*)d_in[3];
    const float* b_o   = (const float*)d_in[4];
    float* outp = (float*)d_out;

    u16* xb    = (u16*)d_ws;
    u16* wqkvb = xb    + (size_t)MROWS * HID;
    u16* wob   = wqkvb + (size_t)QKV3 * HID;
    u16* q_ws  = wob   + (size_t)HID * HID;
    u16* k_ws  = q_ws  + (size_t)MROWS * HID;
    u16* vt_ws = k_ws  + (size_t)MROWS * HID;
    u16* attnb = vt_ws + (size_t)MROWS * HID;

    const int blk = 256;
    cvt_all<<<(N4_X + N4_WQ + N4_WO) / blk, blk, 0, stream>>>(
        x, w_qkv, w_o, xb, wqkvb, wob);

    gemm_bf16_nt<1, 128><<<dim3(QKV3 / 128, MROWS / 128), blk, 0, stream>>>(
        xb, wqkvb, b_qkv, nullptr, MROWS, QKV3, HID, q_ws, k_ws, vt_ws);

    attn_mfma<<<dim3(NH * 2, SEQ / 128), 256, 0, stream>>>(q_ws, k_ws, vt_ws, attnb);

    gemm_bf16_nt<0, 64><<<dim3(HID / 64, MROWS / 128), blk, 0, stream>>>(
        attnb, wob, b_o, outp, MROWS, HID, HID, nullptr, nullptr, nullptr);
}

// Round 10
// 183.428 us; speedup vs baseline: 1.0426x; 1.0044x over previous
//
#include <hip/hip_runtime.h>

// Problem constants (fixed): B=2, S=2048, HIDDEN=1024, NHEADS=16, HEAD_DIM=64.
#define SEQ     2048
#define MROWS   4096
#define HID     1024
#define QKV3    3072
#define NH      16
#define HD      64
#define QSCALE  0.18033688f     // 0.125 * log2(e)  (folded into Q at gemm1)

typedef unsigned short u16;
typedef unsigned int   u32;
typedef __attribute__((ext_vector_type(8)))  short  bf16x8;   // 8 bf16 = 4 VGPRs
typedef __attribute__((ext_vector_type(4)))  float  floatx4;
typedef __attribute__((ext_vector_type(16))) float  floatx16;
typedef __attribute__((ext_vector_type(4)))  unsigned int u32x4;

__device__ __forceinline__ u16 f2bf(float f) {   // round-to-nearest-even
    u32 u = __builtin_bit_cast(u32, f);
    u += 0x7fffu + ((u >> 16) & 1u);
    return (u16)(u >> 16);
}

// raw v_exp_f32 (safe here: |s| < 9, no denormal/range issues)
#if __has_builtin(__builtin_amdgcn_exp2f)
__device__ __forceinline__ float fast_exp2(float x) { return __builtin_amdgcn_exp2f(x); }
#else
__device__ __forceinline__ float fast_exp2(float x) { return exp2f(x); }
#endif

// pack two fp32 -> two bf16 in one dword. low u16 = a, high = b.
#if __has_builtin(__builtin_amdgcn_cvt_pk_bf16_f32)
__device__ __forceinline__ u32 pack_bf(float a, float b) {
    auto r = __builtin_amdgcn_cvt_pk_bf16_f32(a, b);
    return __builtin_bit_cast(u32, r);
}
#else
__device__ __forceinline__ u32 pack_bf(float a, float b) {
    u32 ua = __builtin_bit_cast(u32, a) + 0x8000u;
    u32 ub = __builtin_bit_cast(u32, b) + 0x8000u;
    return __builtin_amdgcn_perm(ub, ua, 0x07060302u);
}
#endif

// v_permlane32_swap_b32: x.high <-> y.low  =>  x' = {x.low | y.low},
// y' = {x.high | y.high} (2x2 half-wave transpose; T12 recipe, m214v22).
__device__ __forceinline__ void plane_swap(u32 &x, u32 &y) {
#if __has_builtin(__builtin_amdgcn_permlane32_swap)
    typedef __attribute__((ext_vector_type(2))) unsigned int u32x2;
    u32x2 r = __builtin_amdgcn_permlane32_swap(x, y, false, false);
    x = r[0]; y = r[1];
#else
    asm volatile("v_permlane32_swap_b32 %0, %1" : "+v"(x), "+v"(y));
#endif
}

// async global->LDS, 16B/lane; LDS dest = wave-uniform base + lane*16
__device__ __forceinline__ void async_cp16(const void* g, void* l) {
    __builtin_amdgcn_global_load_lds(
        (const __attribute__((address_space(1))) unsigned int*)g,
        (__attribute__((address_space(3))) unsigned int*)l, 16, 0, 0);
}

// ---------------------------------------------------------------------------
// Single fused fp32->bf16 conversion over x | w_qkv | w_o (one launch).
// ---------------------------------------------------------------------------
#define N4_X   (MROWS * HID / 4)
#define N4_WQ  (QKV3 * HID / 4)
#define N4_WO  (HID * HID / 4)
__global__ void cvt_all(const float* __restrict__ x, const float* __restrict__ wq,
                        const float* __restrict__ wo, u16* __restrict__ xb,
                        u16* __restrict__ wqb, u16* __restrict__ wob) {
    int i = blockIdx.x * blockDim.x + threadIdx.x;
    const float* src; u16* dst; int k;
    if (i < N4_X)                { src = x;  dst = xb;  k = i; }
    else if (i < N4_X + N4_WQ)   { src = wq; dst = wqb; k = i - N4_X; }
    else                         { src = wo; dst = wob; k = i - N4_X - N4_WQ; }
    float4 v = ((const float4*)src)[k];
    uint2 o = {pack_bf(v.x, v.y), pack_bf(v.z, v.w)};
    ((uint2*)dst)[k] = o;
}

// ---------------------------------------------------------------------------
// C = A @ B^T + bias.  A:[M,K] bf16, B:[N,K] bf16, row-major.
// Tile 128 x NT (NT=128 or 64), BK=32, 4 waves, 32x32x16 MFMA (r18).
// ROUND-19 (T3/T4 counted-vmcnt pipeline): r18 counters — gemm1 = 57.7us,
// ALL pipes idle (Mfma 17.7, VALU 13.2, Occ 15.5, HBM 14.5%), ~1440 cyc/iter
// for ~200 cyc of work = the __syncthreads vmcnt(0) barrier-drain stall
// (stage(t+1) issued ~300cyc before its forced landing). Fix per guide T3/T4
// (m218: counted vs drain-0 = +38-73%): THREE LDS buffers, stage TWO tiles
// ahead, raw s_barrier + s_waitcnt vmcnt(N) so in-flight loads cross the
// barrier. At iter t: outstanding = stage(t+1) only (N=4 loads NT=128 /
// 3 loads NT=64); oldest-first semantics => stage(t) landed. vmcnt(0) on
// final iter. Buffer (t+2)%3 write-after-read safe: all waves' ds_reads of
// it finished before their lgkmcnt(0)->MFMA->barrier last iter. No ds_writes
// in loop => no lgkmcnt at barrier. Uniform control flow (no divergent
// s_barrier). LDS 48KB/36KB -> still 3 blocks/CU.
// ---------------------------------------------------------------------------
template <int MODE, int NT>
__global__ __launch_bounds__(256)
void gemm_bf16_nt(const u16* __restrict__ A, const u16* __restrict__ B,
                  const float* __restrict__ bias, float* __restrict__ Cout,
                  int M, int N, int K,
                  u16* __restrict__ q_ws, u16* __restrict__ k_ws,
                  u16* __restrict__ vt_ws) {
    constexpr int WN = NT / 2;     // per-wave n extent (64 or 32)
    constexpr int NJ = WN / 32;    // 32-wide n-frags per wave (2 or 1)
    // one blob: As[3][128*32] | Bs[3][NT*32]; V-epilogue aliases all of it
    __shared__ __align__(16) u16 smemS[3 * 128 * 32 + 3 * NT * 32];
    auto As_ = [&](int bb) -> u16* { return smemS + bb * 4096; };
    auto Bs_ = [&](int bb) -> u16* { return smemS + 12288 + bb * (NT * 32); };
    const int t  = (int)threadIdx.x;
    const int w  = t >> 6, l = t & 63;
    const int wr = w >> 1, wc = w & 1;
    const int m0 = (int)blockIdx.y * 128, n0 = (int)blockIdx.x * NT;
    const int lrow = l >> 2;
    const int lseg = ((l & 3) ^ ((l >> 3) & 3)) * 8;    // swizzled global seg
    const int ql = l & 31, h = l >> 5;                  // 32x32 frag coords

    auto stage = [&](int k0, int bb) {
#pragma unroll
        for (int rep = 0; rep < 2; ++rep) {
            const int chunk = w + rep * 4;
            const int row   = chunk * 16 + lrow;
            async_cp16(A + (size_t)(m0 + row) * K + k0 + lseg, As_(bb) + chunk * 512);
            if (NT == 128 || rep == 0)
                async_cp16(B + (size_t)(n0 + row) * K + k0 + lseg, Bs_(bb) + chunk * 512);
        }
    };

    const floatx16 z16 = (floatx16)(0.f);
    floatx16 acc[2][NJ];
#pragma unroll
    for (int i = 0; i < 2; ++i)
#pragma unroll
        for (int j = 0; j < NJ; ++j) acc[i][j] = z16;

    const int T = K >> 5;
    stage(0, 0);
    stage(32, 1);
    for (int tt = 0; tt < T; ++tt) {
        const int cur = tt % 3;
        // stage(tt) landed: only stage(tt+1)'s loads may remain in flight
        if (tt + 1 < T) {
            if constexpr (NT == 128) asm volatile("s_waitcnt vmcnt(4)" ::: "memory");
            else                     asm volatile("s_waitcnt vmcnt(3)" ::: "memory");
        } else {
            asm volatile("s_waitcnt vmcnt(0)" ::: "memory");
        }
        __builtin_amdgcn_s_barrier();
        bf16x8 af[2][2], bfr[NJ][2];
#pragma unroll
        for (int i = 0; i < 2; ++i)
#pragma unroll
            for (int ks = 0; ks < 2; ++ks) {
                const int row = wr * 64 + i * 32 + ql;
                const int seg = ((ks * 2 + h) ^ ((ql >> 1) & 3)) * 8;
                af[i][ks] = *(const bf16x8*)(As_(cur) + row * 32 + seg);
            }
#pragma unroll
        for (int j = 0; j < NJ; ++j)
#pragma unroll
            for (int ks = 0; ks < 2; ++ks) {
                const int row = wc * WN + j * 32 + ql;
                const int seg = ((ks * 2 + h) ^ ((ql >> 1) & 3)) * 8;
                bfr[j][ks] = *(const bf16x8*)(Bs_(cur) + row * 32 + seg);
            }
        if (tt + 2 < T) stage((tt + 2) << 5, (tt + 2) % 3);
#pragma unroll
        for (int i = 0; i < 2; ++i)
#pragma unroll
            for (int j = 0; j < NJ; ++j)
#pragma unroll
                for (int ks = 0; ks < 2; ++ks)
                    acc[i][j] = __builtin_amdgcn_mfma_f32_32x32x16_bf16(
                        af[i][ks], bfr[j][ks], acc[i][j], 0, 0, 0);
    }

    // ---- V-region epilogue via LDS (MODE 1, cols 2048..3071) ----
    if (MODE == 1 && (n0 >> 10) == 2) {
        __syncthreads();                      // last tile's ds_reads complete
        u32* VT = (u32*)smemS;                // [128 d][64 s-pair] u32 = 32 KB
#pragma unroll
        for (int j = 0; j < NJ; ++j) {
            const int lc = wc * WN + j * 32 + ql;       // block-local col 0..127
            const float bv = bias[n0 + lc];
#pragma unroll
            for (int i = 0; i < 2; ++i) {
#pragma unroll
                for (int g = 0; g < 4; ++g) {
                    // quad g = 4 consecutive rows rl0 .. rl0+3
                    const int rl0 = wr * 64 + i * 32 + g * 8 + h * 4;
                    const int wp = rl0 >> 1;            // even
                    uint2 pr = {pack_bf(acc[i][j][4*g+0] + bv, acc[i][j][4*g+1] + bv),
                                pack_bf(acc[i][j][4*g+2] + bv, acc[i][j][4*g+3] + bv)};
                    *(uint2*)&VT[lc * 64 + (wp ^ ((lc & 7) << 3))] = pr;
                }
            }
        }
        __syncthreads();
        const int lc = t >> 1, h2 = t & 1;
        const int gcol = n0 + lc;
        const int hh = (gcol >> 6) & 15, d = gcol & 63;
        const int b = m0 >> 11;
        u16* __restrict__ dstp = vt_ws
            + ((size_t)(b * NH + hh) * HD + d) * SEQ + (m0 & 2047) + h2 * 64;
        const int X = (lc & 7) << 3;
#pragma unroll
        for (int c = 0; c < 8; ++c) {
            u32x4 v = *(const u32x4*)&VT[lc * 64 + ((h2 * 32 + c * 4) ^ X)];
            *(u32x4*)&dstp[c * 8] = v;
        }
        return;
    }

    // epilogue: 32x32 C/D layout col = ql, row = (r&3) + 8*(r>>2) + 4h
#pragma unroll
    for (int j = 0; j < NJ; ++j) {
        const int col = n0 + wc * WN + j * 32 + ql;
        const float bv = bias[col];
        const int region = col >> 10;                  // block-uniform in MODE 1
        const int hh = (col >> 6) & 15, d = col & 63;
#pragma unroll
        for (int i = 0; i < 2; ++i) {
#pragma unroll
            for (int g = 0; g < 4; ++g) {
                const int row0 = m0 + wr * 64 + i * 32 + g * 8 + h * 4;
                if (MODE == 0) {
#pragma unroll
                    for (int r = 0; r < 4; ++r)
                        Cout[(size_t)(row0 + r) * N + col] = acc[i][j][4*g+r] + bv;
                } else {
                    u16* __restrict__ dst = (region == 0) ? q_ws : k_ws;
                    const float sc = (region == 0) ? QSCALE : 1.0f;
#pragma unroll
                    for (int r = 0; r < 4; ++r) {
                        const int row = row0 + r;
                        const int b = row >> 11, s = row & 2047;
                        dst[((size_t)(b * NH + hh) * SEQ + s) * HD + d] =
                            f2bf((acc[i][j][4*g+r] + bv) * sc);
                    }
                }
            }
        }
    }
}

// ---------------------------------------------------------------------------
// Flash attention — EXACT round-4/round-7 kernel (verified 48.2 us, thrice).
// 32x32x16 MFMA, operand-swapped (S^T = K Q^T, O^T = V^T P^T), shift-free
// softmax p = exp2(s_scaled). 4 waves x 32 q (qblk 128), BK=128, T12
// in-register P redistribution. r6 key-split (68us) and r8 ILP/setprio
// package (56.5us) both regressed — this structure is the measured optimum;
// leaving it alone.
// ---------------------------------------------------------------------------
__global__ __launch_bounds__(256, 2)
void attn_mfma(const u16* __restrict__ qw, const u16* __restrict__ kw,
               const u16* __restrict__ vtw, u16* __restrict__ attn) {
    __shared__ u16 Ks [2][2][64 * 64];   // [buf][subtile][key][d], swizzled
    __shared__ u16 Vts[2][2][64 * 64];   // [buf][subtile][d][key], swizzled

    const int bh   = (int)blockIdx.x;
    const int qblk = (int)blockIdx.y * 128;
    const int t = (int)threadIdx.x;
    const int w = t >> 6, l = t & 63;          // 4 waves, 32 q each
    const int ql = l & 31, h = l >> 5;         // 32x32 frag: col lane, half
    const int srow = l >> 3, sseg = l & 7;     // staging row/seg in chunk
    const size_t headSD = (size_t)bh * SEQ * HD;
    const size_t headDS = (size_t)bh * HD * SEQ;

    // wave w stages chunks 2w, 2w+1 (8 rows each) of K and V^T, both subtiles
    auto stage = [&](int it, int bb) {
#pragma unroll
        for (int half = 0; half < 2; ++half) {
            const int kt = it * 2 + half;
#pragma unroll
            for (int rep = 0; rep < 2; ++rep) {
                const int chunk = w * 2 + rep;     // 0..7
                async_cp16(kw + headSD + (size_t)(kt * 64 + chunk * 8 + srow) * HD
                               + ((sseg ^ srow) * 8), &Ks[bb][half][chunk * 512]);
                async_cp16(vtw + headDS + (size_t)(chunk * 8 + srow) * SEQ + kt * 64
                               + ((sseg ^ srow) * 8), &Vts[bb][half][chunk * 512]);
            }
        }
    };

    // Q as B-operand frags: B[k = ks*16 + h*8 + e][n = q = ql], from global
    bf16x8 qa[4];
#pragma unroll
    for (int ks = 0; ks < 4; ++ks)
        qa[ks] = *(const bf16x8*)(qw + headSD
            + (size_t)(qblk + w * 32 + ql) * HD + ks * 16 + h * 8);

    const floatx16 z16 = (floatx16)(0.f);      // persistent zero C-operand
    floatx16 oacc[2];
    oacc[0] = z16; oacc[1] = z16;
    float2 psum2 = {0.f, 0.f};

    stage(0, 0);
    for (int it = 0; it < SEQ / 128; ++it) {
        const int cur = it & 1;
        __syncthreads();                    // drains stage(it) (overlapped)
        if (it + 1 < SEQ / 128) stage(it + 1, cur ^ 1);

        // S^T = K Q^T for BOTH subtiles first: sm_A VALU can then overlap
        // QK_B / PV_A MFMAs in the scheduler's single region.
        floatx16 sacc[2][2];
#pragma unroll
        for (int half = 0; half < 2; ++half) {
#pragma unroll
            for (int ks = 0; ks < 4; ++ks) {
                const int seg = ((ks * 2 + h) ^ (ql & 7)) * 8;
#pragma unroll
                for (int t2 = 0; t2 < 2; ++t2) {
                    bf16x8 ka = *(const bf16x8*)&Ks[cur][half][(t2 * 32 + ql) * 64 + seg];
                    sacc[half][t2] = __builtin_amdgcn_mfma_f32_32x32x16_bf16(
                        ka, qa[ks], (ks == 0) ? z16 : sacc[half][t2], 0, 0, 0);
                }
            }
        }

        // softmax + in-register P redistribution (T12) + PV, per subtile.
        // lane holds P(key = t2*32 + (r&3)+8*(r>>2)+4h, q=ql);
        // cvt_pk pairs + permlane32_swap -> PV B-frags, zero LDS.
#pragma unroll
        for (int half = 0; half < 2; ++half) {
#pragma unroll
            for (int t2 = 0; t2 < 2; ++t2) {
                u32 aw[8];
#pragma unroll
                for (int i = 0; i < 8; ++i) {
                    const float p0 = fast_exp2(sacc[half][t2][2 * i]);
                    const float p1 = fast_exp2(sacc[half][t2][2 * i + 1]);
                    psum2 += float2{p0, p1};
                    aw[i] = pack_bf(p0, p1);
                }
                plane_swap(aw[0], aw[2]); plane_swap(aw[1], aw[3]);
                plane_swap(aw[4], aw[6]); plane_swap(aw[5], aw[7]);

#pragma unroll
                for (int ks2 = 0; ks2 < 2; ++ks2) {
                    u32x4 pw = {aw[4 * ks2 + 0], aw[4 * ks2 + 1],
                                aw[4 * ks2 + 2], aw[4 * ks2 + 3]};
                    bf16x8 pb = __builtin_bit_cast(bf16x8, pw);
                    const int seg = ((t2 * 4 + ks2 * 2 + h) ^ (ql & 7)) * 8;
#pragma unroll
                    for (int dt = 0; dt < 2; ++dt) {
                        bf16x8 va = *(const bf16x8*)&Vts[cur][half][(dt * 32 + ql) * 64 + seg];
                        oacc[dt] = __builtin_amdgcn_mfma_f32_32x32x16_bf16(
                            va, pb, oacc[dt], 0, 0, 0);
                    }
                }
            }
        }
    }

    // psum(q): halves hold complementary key sets -> one xor-32 combine
    float psum = psum2.x + psum2.y;
    psum += __shfl_xor(psum, 32);
    const float inv = 1.0f / psum;

    // epilogue: O^T rows = d = (r&3) + 8*(r>>2) + 4h + 32*dt; col q = ql
    const int b = bh >> 4, head = bh & 15;
    u16* __restrict__ orow =
        attn + (size_t)(b * SEQ + qblk + w * 32 + ql) * HID + head * HD;
#pragma unroll
    for (int dt = 0; dt < 2; ++dt) {
#pragma unroll
        for (int g = 0; g < 4; ++g) {
            uint2 o = {pack_bf(oacc[dt][g * 4 + 0] * inv, oacc[dt][g * 4 + 1] * inv),
                       pack_bf(oacc[dt][g * 4 + 2] * inv, oacc[dt][g * 4 + 3] * inv)};
            *(uint2*)&orow[dt * 32 + g * 8 + h * 4] = o;
        }
    }
}

// ---------------------------------------------------------------------------
extern "C" void kernel_launch(void* const* d_in, const int* in_sizes, int n_in,
                              void* d_out, int out_size, void* d_ws, size_t ws_size,
                              hipStream_t stream) {
    const float* x     = (const float*)d_in[0];
    const float* w_qkv = (const float*)d_in[1];
    const float* b_qkv = (const float*)d_in[2];
    const float* w_o   = (const float*)d_in[3];
    const float* b_o   = (const float*)d_in[4];
    float* outp = (float*)d_out;

    u16* xb    = (u16*)d_ws;
    u16* wqkvb = xb    + (size_t)MROWS * HID;
    u16* wob   = wqkvb + (size_t)QKV3 * HID;
    u16* q_ws  = wob   + (size_t)HID * HID;
    u16* k_ws  = q_ws  + (size_t)MROWS * HID;
    u16* vt_ws = k_ws  + (size_t)MROWS * HID;
    u16* attnb = vt_ws + (size_t)MROWS * HID;

    const int blk = 256;
    cvt_all<<<(N4_X + N4_WQ + N4_WO) / blk, blk, 0, stream>>>(
        x, w_qkv, w_o, xb, wqkvb, wob);

    gemm_bf16_nt<1, 128><<<dim3(QKV3 / 128, MROWS / 128), blk, 0, stream>>>(
        xb, wqkvb, b_qkv, nullptr, MROWS, QKV3, HID, q_ws, k_ws, vt_ws);

    attn_mfma<<<dim3(NH * 2, SEQ / 128), 256, 0, stream>>>(q_ws, k_ws, vt_ws, attnb);

    gemm_bf16_nt<0, 64><<<dim3(HID / 64, MROWS / 128), blk, 0, stream>>>(
        attnb, wob, b_o, outp, MROWS, HID, HID, nullptr, nullptr, nullptr);
}